// Round 12
// baseline (239.561 us; speedup 1.0000x reference)
//
#include <hip/hip_runtime.h>

#define B_ 2
#define S_ 2048
#define D_ 2048
#define H_ 16
#define DH_ 128

#define AS1 __attribute__((address_space(1)))
#define AS3 __attribute__((address_space(3)))

typedef __attribute__((ext_vector_type(4))) float f32x4;
typedef __attribute__((ext_vector_type(8))) short bf16x8;

__device__ __forceinline__ unsigned short f2bf(float f) {
  unsigned u = __float_as_uint(f);
  u += 0x7fff + ((u >> 16) & 1);
  return (unsigned short)(u >> 16);
}
__device__ __forceinline__ float bf2f(unsigned short h) {
  return __uint_as_float(((unsigned)h) << 16);
}
__device__ __forceinline__ unsigned cvt_pk_bf16(float lo, float hi) {
  unsigned r;
  asm("v_cvt_pk_bf16_f32 %0, %1, %2" : "=v"(r) : "v"(lo), "v"(hi));
  return r;
}

// One fused cast kernel for x (2097152 f4), wqkv (3145728 f4), wo (1048576 f4).
__global__ __launch_bounds__(256) void cast3(const float* __restrict__ x,
                                             const float* __restrict__ wq,
                                             const float* __restrict__ wo,
                                             unsigned short* __restrict__ xb,
                                             unsigned short* __restrict__ wqb,
                                             unsigned short* __restrict__ wob) {
  int i = blockIdx.x * 256 + threadIdx.x;
  const float* src; unsigned short* dst; int off;
  if (i < 2097152)      { src = x;  dst = xb;  off = i; }
  else if (i < 5242880) { src = wq; dst = wqb; off = i - 2097152; }
  else                  { src = wo; dst = wob; off = i - 5242880; }
  float4 v = reinterpret_cast<const float4*>(src)[off];
  ushort4 o;
  o.x = f2bf(v.x); o.y = f2bf(v.y); o.z = f2bf(v.z); o.w = f2bf(v.w);
  reinterpret_cast<ushort4*>(dst)[off] = o;
}

// ---------------------------------------------------------------------------
// gemm_qkv128: qkv(compact, stride 4096) / Vt = x @ wqkv^T.
// 128x128 tile, dbuf, counted vmcnt(8), 2-phase fine split, setprio;
// 64 KB LDS -> 2 blocks/CU. Unchanged from round 11 (108 us).
// ---------------------------------------------------------------------------
__global__ __launch_bounds__(256) void gemm_qkv128(const unsigned short* __restrict__ A,
                                                   const unsigned short* __restrict__ Bm,
                                                   unsigned short* __restrict__ qkv,
                                                   unsigned short* __restrict__ Vt) {
  __shared__ __align__(16) unsigned short As[2][128*64];  // 2 x 16 KB
  __shared__ __align__(16) unsigned short Bs[2][128*64];  // 2 x 16 KB
  const int t = threadIdx.x;
  const int lane = t & 63;
  const int w = t >> 6;
  const int wm = w >> 1, wn = w & 1;
  const int l16 = lane & 15, lg = lane >> 4;
  const int bm = blockIdx.y, bn = blockIdx.x;
  const int Kdim = 2048;
  const int nkt = 32;

  f32x4 acc[4][4] = {};

#define STGQ(KT)                                                                                   \
  {                                                                                                \
    const int k0s = (KT) * 64;                                                                     \
    const int bufs = (KT) & 1;                                                                     \
    _Pragma("unroll")                                                                              \
    for (int it = 0; it < 4; ++it) {                                                               \
      int e = t*8 + it*2048;                                                                       \
      int row = e >> 6, g = (e >> 3) & 7, gs = g ^ (row & 7);                                      \
      const unsigned short* ga = A  + (size_t)(bm*128 + row)*Kdim + k0s + gs*8;                    \
      const unsigned short* gb = Bm + (size_t)(bn*128 + row)*Kdim + k0s + gs*8;                    \
      __builtin_amdgcn_global_load_lds((const AS1 unsigned int*)ga,                                \
                                       (AS3 unsigned int*)(&As[bufs][e]), 16, 0, 0);               \
      __builtin_amdgcn_global_load_lds((const AS1 unsigned int*)gb,                                \
                                       (AS3 unsigned int*)(&Bs[bufs][e]), 16, 0, 0);               \
    }                                                                                              \
  }

  STGQ(0);
  STGQ(1);

  for (int kt = 0; kt < nkt; ++kt) {
    const int buf = kt & 1;
    if (kt == nkt - 1) { asm volatile("s_waitcnt vmcnt(0)" ::: "memory"); }
    else               { asm volatile("s_waitcnt vmcnt(8)" ::: "memory"); }
    __builtin_amdgcn_s_barrier();
    __builtin_amdgcn_sched_barrier(0);
    bf16x8 a0[4], b0[4];
#pragma unroll
    for (int mi = 0; mi < 4; ++mi) {
      int rowa = wm*64 + mi*16 + l16;
      a0[mi] = *reinterpret_cast<const bf16x8*>(&As[buf][rowa*64 + ((lg ^ (rowa & 7))<<3)]);
      int rowb = wn*64 + mi*16 + l16;
      b0[mi] = *reinterpret_cast<const bf16x8*>(&Bs[buf][rowb*64 + ((lg ^ (rowb & 7))<<3)]);
    }
    asm volatile("s_waitcnt lgkmcnt(0)" ::: "memory");
    __builtin_amdgcn_sched_barrier(0);
    bf16x8 a1[4], b1[4];
#pragma unroll
    for (int mi = 0; mi < 4; ++mi) {
      int g = 4 + lg;
      int rowa = wm*64 + mi*16 + l16;
      a1[mi] = *reinterpret_cast<const bf16x8*>(&As[buf][rowa*64 + ((g ^ (rowa & 7))<<3)]);
      int rowb = wn*64 + mi*16 + l16;
      b1[mi] = *reinterpret_cast<const bf16x8*>(&Bs[buf][rowb*64 + ((g ^ (rowb & 7))<<3)]);
    }
    __builtin_amdgcn_sched_barrier(0);
    __builtin_amdgcn_s_setprio(1);
#pragma unroll
    for (int mi = 0; mi < 4; ++mi)
#pragma unroll
      for (int ni = 0; ni < 4; ++ni)
        acc[mi][ni] = __builtin_amdgcn_mfma_f32_16x16x32_bf16(a0[mi], b0[ni], acc[mi][ni], 0, 0, 0);
    __builtin_amdgcn_s_setprio(0);
    asm volatile("s_waitcnt lgkmcnt(0)" ::: "memory");
    __builtin_amdgcn_sched_barrier(0);
    __builtin_amdgcn_s_barrier();
    if (kt < nkt - 2) STGQ(kt + 2);
    __builtin_amdgcn_s_setprio(1);
#pragma unroll
    for (int mi = 0; mi < 4; ++mi)
#pragma unroll
      for (int ni = 0; ni < 4; ++ni)
        acc[mi][ni] = __builtin_amdgcn_mfma_f32_16x16x32_bf16(a1[mi], b1[ni], acc[mi][ni], 0, 0, 0);
    __builtin_amdgcn_s_setprio(0);
  }
#undef STGQ

  if (bn < 32) {
    // Q or K columns: compact qkv, stride 4096
#pragma unroll
    for (int mi = 0; mi < 4; ++mi) {
#pragma unroll
      for (int ni = 0; ni < 4; ++ni) {
        int col = bn*128 + wn*64 + ni*16 + l16;
        int row0 = bm*128 + wm*64 + mi*16 + lg*4;
#pragma unroll
        for (int r = 0; r < 4; ++r)
          qkv[(size_t)(row0 + r)*4096 + col] = f2bf(acc[mi][ni][r]);
      }
    }
  } else {
    // V columns: write transposed to Vt[b][h][d][s]
#pragma unroll
    for (int mi = 0; mi < 4; ++mi) {
#pragma unroll
      for (int ni = 0; ni < 4; ++ni) {
        int colv = (bn - 32)*128 + wn*64 + ni*16 + l16;
        int h = colv >> 7, d = colv & 127;
        int row0 = bm*128 + wm*64 + mi*16 + lg*4;
        int b = row0 >> 11, s = row0 & 2047;
        ushort4 v4;
        v4.x = f2bf(acc[mi][ni][0]);
        v4.y = f2bf(acc[mi][ni][1]);
        v4.z = f2bf(acc[mi][ni][2]);
        v4.w = f2bf(acc[mi][ni][3]);
        *reinterpret_cast<ushort4*>(&Vt[(((size_t)(b*H_ + h))*DH_ + d)*S_ + s]) = v4;
      }
    }
  }
}

// ---------------------------------------------------------------------------
// gemm_bt: C(f32) = A @ B^T, 128x128 tile, double-buffered, counted vmcnt,
// fine-phase split (output projection). Unchanged from round 8.
// ---------------------------------------------------------------------------
__global__ __launch_bounds__(256) void gemm_bt(const unsigned short* __restrict__ A,
                                               const unsigned short* __restrict__ Bm,
                                               float* __restrict__ C,
                                               int Ndim, int Kdim) {
  __shared__ __align__(16) unsigned short As[2][128*64];  // 2 x 16 KB
  __shared__ __align__(16) unsigned short Bs[2][128*64];  // 2 x 16 KB
  const int t = threadIdx.x;
  const int lane = t & 63;
  const int w = t >> 6;
  const int wm = w >> 1, wn = w & 1;
  const int l16 = lane & 15, lg = lane >> 4;
  const int bm = blockIdx.y, bn = blockIdx.x;
  const int nkt = Kdim >> 6;

  f32x4 acc[4][4] = {};

#define STG2(KT)                                                                                   \
  {                                                                                                \
    const int k0s = (KT) * 64;                                                                     \
    const int bufs = (KT) & 1;                                                                     \
    _Pragma("unroll")                                                                              \
    for (int it = 0; it < 4; ++it) {                                                               \
      int e = t*8 + it*2048;                                                                       \
      int row = e >> 6, g = (e >> 3) & 7, gs = g ^ (row & 7);                                      \
      const unsigned short* ga = A  + (size_t)(bm*128 + row)*Kdim + k0s + gs*8;                    \
      const unsigned short* gb = Bm + (size_t)(bn*128 + row)*Kdim + k0s + gs*8;                    \
      __builtin_amdgcn_global_load_lds((const AS1 unsigned int*)ga,                                \
                                       (AS3 unsigned int*)(&As[bufs][e]), 16, 0, 0);               \
      __builtin_amdgcn_global_load_lds((const AS1 unsigned int*)gb,                                \
                                       (AS3 unsigned int*)(&Bs[bufs][e]), 16, 0, 0);               \
    }                                                                                              \
  }

  STG2(0);
  STG2(1);

  for (int kt = 0; kt < nkt; ++kt) {
    const int buf = kt & 1;
    if (kt == nkt - 1) { asm volatile("s_waitcnt vmcnt(0)" ::: "memory"); }
    else               { asm volatile("s_waitcnt vmcnt(8)" ::: "memory"); }
    __builtin_amdgcn_s_barrier();
    __builtin_amdgcn_sched_barrier(0);
    bf16x8 a0[4], b0[4];
#pragma unroll
    for (int mi = 0; mi < 4; ++mi) {
      int rowa = wm*64 + mi*16 + l16;
      a0[mi] = *reinterpret_cast<const bf16x8*>(&As[buf][rowa*64 + ((lg ^ (rowa & 7))<<3)]);
      int rowb = wn*64 + mi*16 + l16;
      b0[mi] = *reinterpret_cast<const bf16x8*>(&Bs[buf][rowb*64 + ((lg ^ (rowb & 7))<<3)]);
    }
    asm volatile("s_waitcnt lgkmcnt(0)" ::: "memory");
    __builtin_amdgcn_sched_barrier(0);
    bf16x8 a1[4], b1[4];
#pragma unroll
    for (int mi = 0; mi < 4; ++mi) {
      int g = 4 + lg;
      int rowa = wm*64 + mi*16 + l16;
      a1[mi] = *reinterpret_cast<const bf16x8*>(&As[buf][rowa*64 + ((g ^ (rowa & 7))<<3)]);
      int rowb = wn*64 + mi*16 + l16;
      b1[mi] = *reinterpret_cast<const bf16x8*>(&Bs[buf][rowb*64 + ((g ^ (rowb & 7))<<3)]);
    }
    __builtin_amdgcn_sched_barrier(0);
    __builtin_amdgcn_s_setprio(1);
#pragma unroll
    for (int mi = 0; mi < 4; ++mi)
#pragma unroll
      for (int ni = 0; ni < 4; ++ni)
        acc[mi][ni] = __builtin_amdgcn_mfma_f32_16x16x32_bf16(a0[mi], b0[ni], acc[mi][ni], 0, 0, 0);
    __builtin_amdgcn_s_setprio(0);
    asm volatile("s_waitcnt lgkmcnt(0)" ::: "memory");
    __builtin_amdgcn_sched_barrier(0);
    __builtin_amdgcn_s_barrier();
    if (kt < nkt - 2) STG2(kt + 2);
    __builtin_amdgcn_s_setprio(1);
#pragma unroll
    for (int mi = 0; mi < 4; ++mi)
#pragma unroll
      for (int ni = 0; ni < 4; ++ni)
        acc[mi][ni] = __builtin_amdgcn_mfma_f32_16x16x32_bf16(a1[mi], b1[ni], acc[mi][ni], 0, 0, 0);
    __builtin_amdgcn_s_setprio(0);
  }
#undef STG2

#pragma unroll
  for (int mi = 0; mi < 4; ++mi) {
#pragma unroll
    for (int ni = 0; ni < 4; ++ni) {
      int col = bn*128 + wn*64 + ni*16 + l16;
      int row0 = bm*128 + wm*64 + mi*16 + lg*4;
#pragma unroll
      for (int r = 0; r < 4; ++r)
        C[(size_t)(row0 + r) * Ndim + col] = acc[mi][ni][r];
    }
  }
}

// RoPE on q,k from compact qkv (stride 4096), writing Q,K in [B,H,S,DH] bf16.
// Q pre-scaled by (1/sqrt(DH)) * log2(e).
__global__ __launch_bounds__(256) void rope_qk(const unsigned short* __restrict__ qkv,
                                               const float* __restrict__ cosT,
                                               const float* __restrict__ sinT,
                                               unsigned short* __restrict__ Q,
                                               unsigned short* __restrict__ K) {
  const float SCLQ = 0.08838834764831845f * 1.4426950408889634f;
  const int idx = blockIdx.x;
  const int b = idx >> 11, s = idx & 2047;
  const int t = threadIdx.x;
  const int e = t * 8;
  const int h = e >> 7, d0 = e & 127;
  const int j0 = d0 >> 1;
  const size_t rowb = (size_t)(b*S_ + s) * 4096;
  float4 c4 = *reinterpret_cast<const float4*>(&cosT[s*64 + j0]);
  float4 s4 = *reinterpret_cast<const float4*>(&sinT[s*64 + j0]);
  float cc[4] = {c4.x, c4.y, c4.z, c4.w};
  float ss[4] = {s4.x, s4.y, s4.z, s4.w};
  const size_t qo = (((size_t)(b*H_ + h)) * S_ + s) * DH_ + d0;

  ushort4 qv[2], kv[2], qd[2], kd[2];
  qv[0] = *reinterpret_cast<const ushort4*>(&qkv[rowb + e]);
  qv[1] = *reinterpret_cast<const ushort4*>(&qkv[rowb + e + 4]);
  kv[0] = *reinterpret_cast<const ushort4*>(&qkv[rowb + 2048 + e]);
  kv[1] = *reinterpret_cast<const ushort4*>(&qkv[rowb + 2048 + e + 4]);
#pragma unroll
  for (int p = 0; p < 4; ++p) {
    unsigned short* qi = (unsigned short*)&qv[p >> 1] + (p & 1) * 2;
    unsigned short* ki = (unsigned short*)&kv[p >> 1] + (p & 1) * 2;
    unsigned short* qo2 = (unsigned short*)&qd[p >> 1] + (p & 1) * 2;
    unsigned short* ko2 = (unsigned short*)&kd[p >> 1] + (p & 1) * 2;
    float x0 = bf2f(qi[0]), x1 = bf2f(qi[1]);
    qo2[0] = f2bf((x0*cc[p] - x1*ss[p]) * SCLQ);
    qo2[1] = f2bf((x0*ss[p] + x1*cc[p]) * SCLQ);
    float y0 = bf2f(ki[0]), y1 = bf2f(ki[1]);
    ko2[0] = f2bf(y0*cc[p] - y1*ss[p]);
    ko2[1] = f2bf(y0*ss[p] + y1*cc[p]);
  }
  *reinterpret_cast<ushort4*>(&Q[qo])     = qd[0];
  *reinterpret_cast<ushort4*>(&Q[qo + 4]) = qd[1];
  *reinterpret_cast<ushort4*>(&K[qo])     = kd[0];
  *reinterpret_cast<ushort4*>(&K[qo + 4]) = kd[1];
}

// ---------------------------------------------------------------------------
// Flash attention, causal. UN-PAIRED: one 128-row q-tile per block (8 waves x
// 16 rows), LPT dispatch (longest blocks first -> dynamic CU assignment
// balances), head->XCD affinity (bh = bid&31 so bh%8 fixed per head).
// K/V double-buffered; swapped QK^T softmax, defer-rescale, setprio.
// Block x: ntiles = 2x+2; wave w diagonal tile = 2x + (w>>2).
// ---------------------------------------------------------------------------
__global__ __launch_bounds__(512) void attn(const unsigned short* __restrict__ Q,
                                            const unsigned short* __restrict__ K,
                                            const unsigned short* __restrict__ Vt,
                                            unsigned short* __restrict__ O) {
  __shared__ __align__(16) unsigned short Ks[2][64*128];   // 32 KB
  __shared__ __align__(16) unsigned short Vs[2][128*64];   // 32 KB
  __shared__ __align__(16) unsigned short Plds[8][16*64];  // 16 KB  (total 80 KB)
  const int bid = blockIdx.x;
  const int x = 15 - (bid >> 5);       // descending work: x=15 blocks dispatch first
  const int bh = bid & 31;             // head XCD-affinity: bh%8 fixed per head
  const int b = bh >> 4, h = bh & 15;
  const int t = threadIdx.x;
  const int lane = t & 63;
  const int w = t >> 6;                // 0..7
  const int l16 = lane & 15, lg = lane >> 4;
  const int q0 = x * 128 + w * 16;
  const int qtw = 2*x + (w >> 2);      // this wave's diagonal tile
  const unsigned short* Qh = Q  + (size_t)bh * S_ * DH_;
  const unsigned short* Kh = K  + (size_t)bh * S_ * DH_;
  const unsigned short* Vh = Vt + (size_t)bh * DH_ * S_;

  bf16x8 aq[4];
#pragma unroll
  for (int kk = 0; kk < 4; ++kk)
    aq[kk] = *reinterpret_cast<const bf16x8*>(Qh + (size_t)(q0 + l16)*DH_ + kk*32 + lg*8);

  f32x4 o[8] = {};
  float mrun = -1e30f, lrun = 0.f;
  const int ntiles = 2*x + 2;

#define STAGE_KV(TILE)                                                                              \
  {                                                                                                 \
    const int kv0s = (TILE) * 64;                                                                   \
    unsigned short* Kd = &Ks[(TILE) & 1][0];                                                        \
    unsigned short* Vd = &Vs[(TILE) & 1][0];                                                        \
    _Pragma("unroll")                                                                               \
    for (int it = 0; it < 2; ++it) {                                                                \
      int e = t*8 + it*4096;                                                                        \
      int row = e >> 7;                                                                             \
      int gslot = (e >> 3) & 15;                                                                    \
      int gsrc = gslot ^ (row & 7);                                                                 \
      const unsigned short* ga = Kh + (size_t)(kv0s + row) * DH_ + gsrc*8;                          \
      __builtin_amdgcn_global_load_lds((const AS1 unsigned int*)ga,                                 \
                                       (AS3 unsigned int*)(&Kd[e]), 16, 0, 0);                      \
    }                                                                                               \
    _Pragma("unroll")                                                                               \
    for (int it = 0; it < 2; ++it) {                                                                \
      int e = t*8 + it*4096;                                                                        \
      int dd = e >> 6;                                                                              \
      int gslot = (e >> 3) & 7;                                                                     \
      int gsrc = gslot ^ (dd & 7);                                                                  \
      const unsigned short* gv = Vh + (size_t)dd * S_ + kv0s + gsrc*8;                              \
      __builtin_amdgcn_global_load_lds((const AS1 unsigned int*)gv,                                 \
                                       (AS3 unsigned int*)(&Vd[e]), 16, 0, 0);                      \
    }                                                                                               \
  }

  STAGE_KV(0);

  for (int tile = 0; tile < ntiles; ++tile) {
    __syncthreads();                       // stage(tile) landed
    if (tile + 1 < ntiles) STAGE_KV(tile + 1);   // overlaps with compute below
    const int kv0 = tile * 64;
    const int buf = tile & 1;

    if (tile <= qtw) {
      f32x4 sc[4] = {};
      __builtin_amdgcn_s_setprio(1);
#pragma unroll
      for (int kk = 0; kk < 4; ++kk) {
#pragma unroll
        for (int n = 0; n < 4; ++n) {
          int row = n*16 + l16;
          int g = kk*4 + lg;
          bf16x8 bk = *reinterpret_cast<const bf16x8*>(&Ks[buf][row*128 + ((g ^ (row & 7))<<3)]);
          sc[n] = __builtin_amdgcn_mfma_f32_16x16x32_bf16(bk, aq[kk], sc[n], 0, 0, 0);
        }
      }
      __builtin_amdgcn_s_setprio(0);
      if (tile == qtw) {
        int qrow = q0 + l16;
#pragma unroll
        for (int n = 0; n < 4; ++n)
#pragma unroll
          for (int r = 0; r < 4; ++r) {
            int kidx = kv0 + n*16 + lg*4 + r;
            sc[n][r] = (kidx > qrow) ? -1e30f : sc[n][r];
          }
      }
      float mt = sc[0][0];
#pragma unroll
      for (int n = 0; n < 4; ++n)
#pragma unroll
        for (int r = 0; r < 4; ++r) mt = fmaxf(mt, sc[n][r]);
      mt = fmaxf(mt, __shfl_xor(mt, 16));
      mt = fmaxf(mt, __shfl_xor(mt, 32));
      if (__any(mt > mrun + 8.f)) {
        float mnew = fmaxf(mrun, mt);
        float alpha = __builtin_amdgcn_exp2f(mrun - mnew);
        mrun = mnew;
        lrun *= alpha;
        float ar[4];
#pragma unroll
        for (int r = 0; r < 4; ++r) ar[r] = __shfl(alpha, lg*4 + r);
#pragma unroll
        for (int n2 = 0; n2 < 8; ++n2)
#pragma unroll
          for (int r = 0; r < 4; ++r) o[n2][r] *= ar[r];
      }
      float rs = 0.f;
      unsigned pk[4][2];
#pragma unroll
      for (int n = 0; n < 4; ++n) {
        float p0 = __builtin_amdgcn_exp2f(sc[n][0] - mrun);
        float p1 = __builtin_amdgcn_exp2f(sc[n][1] - mrun);
        float p2 = __builtin_amdgcn_exp2f(sc[n][2] - mrun);
        float p3 = __builtin_amdgcn_exp2f(sc[n][3] - mrun);
        rs += (p0 + p1) + (p2 + p3);
        pk[n][0] = cvt_pk_bf16(p0, p1);
        pk[n][1] = cvt_pk_bf16(p2, p3);
      }
      rs += __shfl_xor(rs, 16);
      rs += __shfl_xor(rs, 32);
      lrun += rs;
      unsigned short* Pw = &Plds[w][0];
      char* Pb = (char*)Pw + l16*128;
#pragma unroll
      for (int n = 0; n < 4; ++n) {
        int sslot = (n*4 + lg) ^ (l16 & 14);
        *reinterpret_cast<uint2*>(Pb + sslot*8) = make_uint2(pk[n][0], pk[n][1]);
      }
      bf16x8 pa[2];
#pragma unroll
      for (int kk2 = 0; kk2 < 2; ++kk2) {
        int tp = (kk2*4 + lg) ^ ((l16 >> 1) & 7);
        pa[kk2] = *reinterpret_cast<const bf16x8*>(Pb + tp*16);
      }
      __builtin_amdgcn_s_setprio(1);
#pragma unroll
      for (int kk2 = 0; kk2 < 2; ++kk2) {
#pragma unroll
        for (int n2 = 0; n2 < 8; ++n2) {
          int d = n2*16 + l16;
          int g = kk2*4 + lg;
          bf16x8 bv = *reinterpret_cast<const bf16x8*>(&Vs[buf][d*64 + ((g ^ (d & 7))<<3)]);
          o[n2] = __builtin_amdgcn_mfma_f32_16x16x32_bf16(pa[kk2], bv, o[n2], 0, 0, 0);
        }
      }
      __builtin_amdgcn_s_setprio(0);
    }
  }
  float linv = 1.f / lrun;
  float lr[4];
#pragma unroll
  for (int r = 0; r < 4; ++r) lr[r] = __shfl(linv, lg*4 + r);
  size_t ob = ((size_t)b * S_) * D_;
#pragma unroll
  for (int n2 = 0; n2 < 8; ++n2) {
#pragma unroll
    for (int r = 0; r < 4; ++r) {
      int rowq = q0 + lg*4 + r;
      int d = n2*16 + l16;
      O[ob + (size_t)rowq * D_ + h*DH_ + d] = f2bf(o[n2][r] * lr[r]);
    }
  }
}

extern "C" void kernel_launch(void* const* d_in, const int* in_sizes, int n_in,
                              void* d_out, int out_size, void* d_ws, size_t ws_size,
                              hipStream_t stream) {
  const float* x    = (const float*)d_in[0];
  const float* fcos = (const float*)d_in[1];
  const float* fsin = (const float*)d_in[2];
  const float* wqkv = (const float*)d_in[4];
  const float* wo   = (const float*)d_in[5];
  float* out = (float*)d_out;
  char* ws = (char*)d_ws;

  unsigned short* xb    = (unsigned short*)(ws);                 // 16,777,216 B
  unsigned short* wqkvb = (unsigned short*)(ws + 16777216);      // 25,165,824 B
  unsigned short* wob   = (unsigned short*)(ws + 41943040);      //  8,388,608 B
  unsigned short* qkv   = (unsigned short*)(ws + 50331648);      // 33,554,432 B (compact QK, stride 4096)
  unsigned short* Qb    = (unsigned short*)(ws + 83886080);      // 16,777,216 B
  unsigned short* Kb    = (unsigned short*)(ws + 100663296);     // 16,777,216 B
  unsigned short* Vtb   = (unsigned short*)(ws + 117440512);     // 16,777,216 B (end 134,217,728)
  unsigned short* attn_out = xb;  // xb dead after gemm_qkv128 -> reuse

  cast3<<<dim3(24576), 256, 0, stream>>>(x, wqkv, wo, xb, wqkvb, wob);

  gemm_qkv128<<<dim3(48, 32), 256, 0, stream>>>(xb, wqkvb, qkv, Vtb);
  rope_qk<<<dim3(4096), 256, 0, stream>>>(qkv, fcos, fsin, Qb, Kb);
  attn<<<dim3(512), 512, 0, stream>>>(Qb, Kb, Vtb, attn_out);
  gemm_bt<<<dim3(16, 32), 256, 0, stream>>>(attn_out, wob, out, 2048, 2048);
}

// Round 13
// 228.235 us; speedup vs baseline: 1.0496x; 1.0496x over previous
//
#include <hip/hip_runtime.h>

#define B_ 2
#define S_ 2048
#define D_ 2048
#define H_ 16
#define DH_ 128

#define AS1 __attribute__((address_space(1)))
#define AS3 __attribute__((address_space(3)))

typedef __attribute__((ext_vector_type(4))) float f32x4;
typedef __attribute__((ext_vector_type(8))) short bf16x8;
typedef __attribute__((ext_vector_type(4))) unsigned int u32x4;

__device__ __forceinline__ unsigned short f2bf(float f) {
  unsigned u = __float_as_uint(f);
  u += 0x7fff + ((u >> 16) & 1);
  return (unsigned short)(u >> 16);
}
__device__ __forceinline__ float bf2f(unsigned short h) {
  return __uint_as_float(((unsigned)h) << 16);
}
__device__ __forceinline__ unsigned cvt_pk_bf16(float lo, float hi) {
  unsigned r;
  asm("v_cvt_pk_bf16_f32 %0, %1, %2" : "=v"(r) : "v"(lo), "v"(hi));
  return r;
}
// rope one (even,odd) pair -> packed 2xbf16, with scale folded in
__device__ __forceinline__ unsigned rope2(unsigned short e, unsigned short o_,
                                          float c, float s, float scl) {
  float x0 = bf2f(e), x1 = bf2f(o_);
  return cvt_pk_bf16((x0*c - x1*s)*scl, (x0*s + x1*c)*scl);
}

// One fused cast kernel for x (2097152 f4), wqkv (3145728 f4), wo (1048576 f4).
__global__ __launch_bounds__(256) void cast3(const float* __restrict__ x,
                                             const float* __restrict__ wq,
                                             const float* __restrict__ wo,
                                             unsigned short* __restrict__ xb,
                                             unsigned short* __restrict__ wqb,
                                             unsigned short* __restrict__ wob) {
  int i = blockIdx.x * 256 + threadIdx.x;
  const float* src; unsigned short* dst; int off;
  if (i < 2097152)      { src = x;  dst = xb;  off = i; }
  else if (i < 5242880) { src = wq; dst = wqb; off = i - 2097152; }
  else                  { src = wo; dst = wob; off = i - 5242880; }
  float4 v = reinterpret_cast<const float4*>(src)[off];
  ushort4 o;
  o.x = f2bf(v.x); o.y = f2bf(v.y); o.z = f2bf(v.z); o.w = f2bf(v.w);
  reinterpret_cast<ushort4*>(dst)[off] = o;
}

// ---------------------------------------------------------------------------
// gemm_qkv256: qkv(compact, stride 4096) / Vt = x @ wqkv^T.
// 256x192 tile, BK=64, 8 waves (2x4), per-wave 128x48 (acc[8][3]).
// Round-8 fine-phase K-tile (107 us): {vmcnt(7); bar; R_kk0; lgkm0;
// R_kk1-issue; MFMA_kk0; lgkm0; bar; STG(kt+2); MFMA_kk1}.
// ---------------------------------------------------------------------------
__global__ __launch_bounds__(512) void gemm_qkv256(const unsigned short* __restrict__ A,
                                                   const unsigned short* __restrict__ Bm,
                                                   unsigned short* __restrict__ qkv,
                                                   unsigned short* __restrict__ Vt) {
  __shared__ __align__(16) unsigned short As[2][256*64];  // 2 x 32 KB
  __shared__ __align__(16) unsigned short Bs[2][192*64];  // 2 x 24 KB
  const int t = threadIdx.x;          // 0..511
  const int lane = t & 63;
  const int w = t >> 6;
  const int wr = w >> 2, wc = w & 3;  // 2 x 4 wave grid
  const int l16 = lane & 15, lg = lane >> 4;
  const int bm = blockIdx.y, bn = blockIdx.x;

  f32x4 acc[8][3] = {};

#define STG1(KT)                                                                                   \
  {                                                                                                \
    const int k0s = (KT) * 64;                                                                     \
    const int bufs = (KT) & 1;                                                                     \
    _Pragma("unroll")                                                                              \
    for (int rr = 0; rr < 4; ++rr) {                                                               \
      int e = t*8 + rr*4096;                                                                       \
      int row = e >> 6, g = (e >> 3) & 7, gs = g ^ (row & 7);                                      \
      const unsigned short* ga = A + (size_t)(bm*256 + row)*2048 + k0s + gs*8;                     \
      __builtin_amdgcn_global_load_lds((const AS1 unsigned int*)ga,                                \
                                       (AS3 unsigned int*)(&As[bufs][e]), 16, 0, 0);               \
    }                                                                                              \
    _Pragma("unroll")                                                                              \
    for (int rr = 0; rr < 3; ++rr) {                                                               \
      int e = t*8 + rr*4096;                                                                       \
      int row = e >> 6, g = (e >> 3) & 7, gs = g ^ (row & 7);                                      \
      const unsigned short* gb = Bm + (size_t)(bn*192 + row)*2048 + k0s + gs*8;                    \
      __builtin_amdgcn_global_load_lds((const AS1 unsigned int*)gb,                                \
                                       (AS3 unsigned int*)(&Bs[bufs][e]), 16, 0, 0);               \
    }                                                                                              \
  }

  STG1(0);
  STG1(1);

  for (int kt = 0; kt < 32; ++kt) {
    const int buf = kt & 1;
    if (kt == 31) { asm volatile("s_waitcnt vmcnt(0)" ::: "memory"); }
    else          { asm volatile("s_waitcnt vmcnt(7)" ::: "memory"); }
    __builtin_amdgcn_s_barrier();
    __builtin_amdgcn_sched_barrier(0);
    // R kk=0 (11 x ds_read_b128)
    bf16x8 a0[8], b0[3];
#pragma unroll
    for (int ni = 0; ni < 3; ++ni) {
      int row = wc*48 + ni*16 + l16;
      b0[ni] = *reinterpret_cast<const bf16x8*>(&Bs[buf][row*64 + ((lg ^ (row & 7))<<3)]);
    }
#pragma unroll
    for (int m8 = 0; m8 < 8; ++m8) {
      int row = wr*128 + m8*16 + l16;
      a0[m8] = *reinterpret_cast<const bf16x8*>(&As[buf][row*64 + ((lg ^ (row & 7))<<3)]);
    }
    asm volatile("s_waitcnt lgkmcnt(0)" ::: "memory");
    __builtin_amdgcn_sched_barrier(0);
    // R kk=1 issue (latency hides under MFMA_kk0)
    bf16x8 a1[8], b1[3];
#pragma unroll
    for (int ni = 0; ni < 3; ++ni) {
      int row = wc*48 + ni*16 + l16;
      int g = 4 + lg;
      b1[ni] = *reinterpret_cast<const bf16x8*>(&Bs[buf][row*64 + ((g ^ (row & 7))<<3)]);
    }
#pragma unroll
    for (int m8 = 0; m8 < 8; ++m8) {
      int row = wr*128 + m8*16 + l16;
      int g = 4 + lg;
      a1[m8] = *reinterpret_cast<const bf16x8*>(&As[buf][row*64 + ((g ^ (row & 7))<<3)]);
    }
    __builtin_amdgcn_sched_barrier(0);
    // MFMA kk=0 (24)
    __builtin_amdgcn_s_setprio(1);
#pragma unroll
    for (int m8 = 0; m8 < 8; ++m8)
#pragma unroll
      for (int ni = 0; ni < 3; ++ni)
        acc[m8][ni] = __builtin_amdgcn_mfma_f32_16x16x32_bf16(a0[m8], b0[ni], acc[m8][ni], 0, 0, 0);
    __builtin_amdgcn_s_setprio(0);
    asm volatile("s_waitcnt lgkmcnt(0)" ::: "memory");   // my kk1 reads done
    __builtin_amdgcn_sched_barrier(0);
    __builtin_amdgcn_s_barrier();          // ALL waves done reading buf[kt&1]
    if (kt < 30) STG1(kt + 2);             // overwrite buf[kt&1]; hides under MFMA_kk1
    // MFMA kk=1 (24)
    __builtin_amdgcn_s_setprio(1);
#pragma unroll
    for (int m8 = 0; m8 < 8; ++m8)
#pragma unroll
      for (int ni = 0; ni < 3; ++ni)
        acc[m8][ni] = __builtin_amdgcn_mfma_f32_16x16x32_bf16(a1[m8], b1[ni], acc[m8][ni], 0, 0, 0);
    __builtin_amdgcn_s_setprio(0);
  }
#undef STG1

#pragma unroll
  for (int mi = 0; mi < 8; ++mi) {
#pragma unroll
    for (int ni = 0; ni < 3; ++ni) {
      int col = bn*192 + wc*48 + ni*16 + l16;
      int row0 = bm*256 + wr*128 + mi*16 + lg*4;
      if (col < 4096) {
        // Q or K: compact qkv, stride 4096
#pragma unroll
        for (int r = 0; r < 4; ++r)
          qkv[(size_t)(row0 + r)*4096 + col] = f2bf(acc[mi][ni][r]);
      } else {
        // V: write transposed to Vt[b][h][d][s]
        int colv = col - 4096;
        int h = colv >> 7, d = colv & 127;
        int b = row0 >> 11, s = row0 & 2047;
        ushort4 v4;
        v4.x = f2bf(acc[mi][ni][0]);
        v4.y = f2bf(acc[mi][ni][1]);
        v4.z = f2bf(acc[mi][ni][2]);
        v4.w = f2bf(acc[mi][ni][3]);
        *reinterpret_cast<ushort4*>(&Vt[(((size_t)(b*H_ + h))*DH_ + d)*S_ + s]) = v4;
      }
    }
  }
}

// ---------------------------------------------------------------------------
// gemm_bt: C(f32) = A @ B^T, 128x128 tile, double-buffered, counted vmcnt,
// fine-phase split (output projection). Unchanged from round 8.
// ---------------------------------------------------------------------------
__global__ __launch_bounds__(256) void gemm_bt(const unsigned short* __restrict__ A,
                                               const unsigned short* __restrict__ Bm,
                                               float* __restrict__ C,
                                               int Ndim, int Kdim) {
  __shared__ __align__(16) unsigned short As[2][128*64];  // 2 x 16 KB
  __shared__ __align__(16) unsigned short Bs[2][128*64];  // 2 x 16 KB
  const int t = threadIdx.x;
  const int lane = t & 63;
  const int w = t >> 6;
  const int wm = w >> 1, wn = w & 1;
  const int l16 = lane & 15, lg = lane >> 4;
  const int bm = blockIdx.y, bn = blockIdx.x;
  const int nkt = Kdim >> 6;

  f32x4 acc[4][4] = {};

#define STG2(KT)                                                                                   \
  {                                                                                                \
    const int k0s = (KT) * 64;                                                                     \
    const int bufs = (KT) & 1;                                                                     \
    _Pragma("unroll")                                                                              \
    for (int it = 0; it < 4; ++it) {                                                               \
      int e = t*8 + it*2048;                                                                       \
      int row = e >> 6, g = (e >> 3) & 7, gs = g ^ (row & 7);                                      \
      const unsigned short* ga = A  + (size_t)(bm*128 + row)*Kdim + k0s + gs*8;                    \
      const unsigned short* gb = Bm + (size_t)(bn*128 + row)*Kdim + k0s + gs*8;                    \
      __builtin_amdgcn_global_load_lds((const AS1 unsigned int*)ga,                                \
                                       (AS3 unsigned int*)(&As[bufs][e]), 16, 0, 0);               \
      __builtin_amdgcn_global_load_lds((const AS1 unsigned int*)gb,                                \
                                       (AS3 unsigned int*)(&Bs[bufs][e]), 16, 0, 0);               \
    }                                                                                              \
  }

  STG2(0);
  STG2(1);

  for (int kt = 0; kt < nkt; ++kt) {
    const int buf = kt & 1;
    if (kt == nkt - 1) { asm volatile("s_waitcnt vmcnt(0)" ::: "memory"); }
    else               { asm volatile("s_waitcnt vmcnt(8)" ::: "memory"); }
    __builtin_amdgcn_s_barrier();
    __builtin_amdgcn_sched_barrier(0);
    bf16x8 a0[4], b0[4];
#pragma unroll
    for (int mi = 0; mi < 4; ++mi) {
      int rowa = wm*64 + mi*16 + l16;
      a0[mi] = *reinterpret_cast<const bf16x8*>(&As[buf][rowa*64 + ((lg ^ (rowa & 7))<<3)]);
      int rowb = wn*64 + mi*16 + l16;
      b0[mi] = *reinterpret_cast<const bf16x8*>(&Bs[buf][rowb*64 + ((lg ^ (rowb & 7))<<3)]);
    }
    asm volatile("s_waitcnt lgkmcnt(0)" ::: "memory");
    __builtin_amdgcn_sched_barrier(0);
    bf16x8 a1[4], b1[4];
#pragma unroll
    for (int mi = 0; mi < 4; ++mi) {
      int g = 4 + lg;
      int rowa = wm*64 + mi*16 + l16;
      a1[mi] = *reinterpret_cast<const bf16x8*>(&As[buf][rowa*64 + ((g ^ (rowa & 7))<<3)]);
      int rowb = wn*64 + mi*16 + l16;
      b1[mi] = *reinterpret_cast<const bf16x8*>(&Bs[buf][rowb*64 + ((g ^ (rowb & 7))<<3)]);
    }
    __builtin_amdgcn_sched_barrier(0);
    __builtin_amdgcn_s_setprio(1);
#pragma unroll
    for (int mi = 0; mi < 4; ++mi)
#pragma unroll
      for (int ni = 0; ni < 4; ++ni)
        acc[mi][ni] = __builtin_amdgcn_mfma_f32_16x16x32_bf16(a0[mi], b0[ni], acc[mi][ni], 0, 0, 0);
    __builtin_amdgcn_s_setprio(0);
    asm volatile("s_waitcnt lgkmcnt(0)" ::: "memory");
    __builtin_amdgcn_sched_barrier(0);
    __builtin_amdgcn_s_barrier();
    if (kt < nkt - 2) STG2(kt + 2);
    __builtin_amdgcn_s_setprio(1);
#pragma unroll
    for (int mi = 0; mi < 4; ++mi)
#pragma unroll
      for (int ni = 0; ni < 4; ++ni)
        acc[mi][ni] = __builtin_amdgcn_mfma_f32_16x16x32_bf16(a1[mi], b1[ni], acc[mi][ni], 0, 0, 0);
    __builtin_amdgcn_s_setprio(0);
  }
#undef STG2

#pragma unroll
  for (int mi = 0; mi < 4; ++mi) {
#pragma unroll
    for (int ni = 0; ni < 4; ++ni) {
      int col = bn*128 + wn*64 + ni*16 + l16;
      int row0 = bm*128 + wm*64 + mi*16 + lg*4;
#pragma unroll
      for (int r = 0; r < 4; ++r)
        C[(size_t)(row0 + r) * Ndim + col] = acc[mi][ni][r];
    }
  }
}

// RoPE on K ONLY from compact qkv (stride 4096), writing K in [B,H,S,DH] bf16.
// (Q-RoPE is fused into attn's Q-fragment load.)
__global__ __launch_bounds__(256) void rope_k(const unsigned short* __restrict__ qkv,
                                              const float* __restrict__ cosT,
                                              const float* __restrict__ sinT,
                                              unsigned short* __restrict__ K) {
  const int idx = blockIdx.x;
  const int b = idx >> 11, s = idx & 2047;
  const int t = threadIdx.x;
  const int e = t * 8;
  const int h = e >> 7, d0 = e & 127;
  const int j0 = d0 >> 1;
  const size_t rowb = (size_t)(b*S_ + s) * 4096;
  float4 c4 = *reinterpret_cast<const float4*>(&cosT[s*64 + j0]);
  float4 s4 = *reinterpret_cast<const float4*>(&sinT[s*64 + j0]);
  float cc[4] = {c4.x, c4.y, c4.z, c4.w};
  float ss[4] = {s4.x, s4.y, s4.z, s4.w};
  const size_t ko = (((size_t)(b*H_ + h)) * S_ + s) * DH_ + d0;

  ushort4 kv[2], kd[2];
  kv[0] = *reinterpret_cast<const ushort4*>(&qkv[rowb + 2048 + e]);
  kv[1] = *reinterpret_cast<const ushort4*>(&qkv[rowb + 2048 + e + 4]);
#pragma unroll
  for (int p = 0; p < 4; ++p) {
    unsigned short* ki = (unsigned short*)&kv[p >> 1] + (p & 1) * 2;
    unsigned short* ko2 = (unsigned short*)&kd[p >> 1] + (p & 1) * 2;
    float y0 = bf2f(ki[0]), y1 = bf2f(ki[1]);
    ko2[0] = f2bf(y0*cc[p] - y1*ss[p]);
    ko2[1] = f2bf(y0*ss[p] + y1*cc[p]);
  }
  *reinterpret_cast<ushort4*>(&K[ko])     = kd[0];
  *reinterpret_cast<ushort4*>(&K[ko + 4]) = kd[1];
}

// ---------------------------------------------------------------------------
// Flash attention, causal. 8 waves/block, PAIRED q-tiles (uniform 33-unit
// blocks, all-resident 2/CU); K/V DOUBLE-BUFFERED; swapped QK^T softmax,
// defer-rescale, setprio, XCD-chunked block swizzle. Q read directly from
// compact qkv with IN-REGISTER RoPE + scale (once per block).
// ---------------------------------------------------------------------------
#define NQT 32
__global__ __launch_bounds__(512) void attn(const unsigned short* __restrict__ qkvc,
                                            const unsigned short* __restrict__ K,
                                            const unsigned short* __restrict__ Vt,
                                            const float* __restrict__ cosT,
                                            const float* __restrict__ sinT,
                                            unsigned short* __restrict__ O) {
  __shared__ __align__(16) unsigned short Ks[2][64*128];   // 32 KB
  __shared__ __align__(16) unsigned short Vs[2][128*64];   // 32 KB
  __shared__ __align__(16) unsigned short Plds[8][16*64];  // 16 KB  (total 80 KB)
  const float SCLQ = 0.08838834764831845f * 1.4426950408889634f;
  const int orig = blockIdx.y * gridDim.x + blockIdx.x;
  const int wgid = (orig & 7) * 64 + (orig >> 3);   // 512 wgs, 64 per XCD
  const int x = wgid & 15;
  const int bh = wgid >> 4;
  const int b = bh >> 4, h = bh & 15;
  const int t = threadIdx.x;
  const int lane = t & 63;
  const int w = t >> 6;
  const int wg8 = w >> 2;              // 0: tile a, 1: tile b
  const int wi = w & 3;
  const int l16 = lane & 15, lg = lane >> 4;
  const int qt = wg8 ? (NQT - 1 - x) : x;
  const int q0 = qt * 64 + wi * 16;
  const unsigned short* Kh = K  + (size_t)bh * S_ * DH_;
  const unsigned short* Vh = Vt + (size_t)bh * DH_ * S_;

  // Q frags from compact qkv + in-register RoPE (pairs adjacent in-lane)
  bf16x8 aq[4];
  {
    const int s = q0 + l16;
    const size_t rowb = (size_t)(b*S_ + s) * 4096 + h*DH_;
#pragma unroll
    for (int kk = 0; kk < 4; ++kk) {
      int d0 = kk*32 + lg*8;
      ushort4 v0 = *reinterpret_cast<const ushort4*>(&qkvc[rowb + d0]);
      ushort4 v1 = *reinterpret_cast<const ushort4*>(&qkvc[rowb + d0 + 4]);
      int j0 = kk*16 + lg*4;
      float4 c4 = *reinterpret_cast<const float4*>(&cosT[s*64 + j0]);
      float4 s4 = *reinterpret_cast<const float4*>(&sinT[s*64 + j0]);
      u32x4 pk4;
      pk4[0] = rope2(v0.x, v0.y, c4.x, s4.x, SCLQ);
      pk4[1] = rope2(v0.z, v0.w, c4.y, s4.y, SCLQ);
      pk4[2] = rope2(v1.x, v1.y, c4.z, s4.z, SCLQ);
      pk4[3] = rope2(v1.z, v1.w, c4.w, s4.w, SCLQ);
      aq[kk] = *reinterpret_cast<bf16x8*>(&pk4);
    }
  }

  f32x4 o[8] = {};
  float mrun = -1e30f, lrun = 0.f;
  const int ntiles = NQT - x;

#define STAGE_KV(TILE)                                                                              \
  {                                                                                                 \
    const int kv0s = (TILE) * 64;                                                                   \
    unsigned short* Kd = &Ks[(TILE) & 1][0];                                                        \
    unsigned short* Vd = &Vs[(TILE) & 1][0];                                                        \
    _Pragma("unroll")                                                                               \
    for (int it = 0; it < 2; ++it) {                                                                \
      int e = t*8 + it*4096;                                                                        \
      int row = e >> 7;                                                                             \
      int gslot = (e >> 3) & 15;                                                                    \
      int gsrc = gslot ^ (row & 7);                                                                 \
      const unsigned short* ga = Kh + (size_t)(kv0s + row) * DH_ + gsrc*8;                          \
      __builtin_amdgcn_global_load_lds((const AS1 unsigned int*)ga,                                 \
                                       (AS3 unsigned int*)(&Kd[e]), 16, 0, 0);                      \
    }                                                                                               \
    _Pragma("unroll")                                                                               \
    for (int it = 0; it < 2; ++it) {                                                                \
      int e = t*8 + it*4096;                                                                        \
      int dd = e >> 6;                                                                              \
      int gslot = (e >> 3) & 7;                                                                     \
      int gsrc = gslot ^ (dd & 7);                                                                  \
      const unsigned short* gv = Vh + (size_t)dd * S_ + kv0s + gsrc*8;                              \
      __builtin_amdgcn_global_load_lds((const AS1 unsigned int*)gv,                                 \
                                       (AS3 unsigned int*)(&Vd[e]), 16, 0, 0);                      \
    }                                                                                               \
  }

  STAGE_KV(0);

  for (int tile = 0; tile < ntiles; ++tile) {
    __syncthreads();                       // stage(tile) landed
    if (tile + 1 < ntiles) STAGE_KV(tile + 1);   // overlaps with compute below
    const int kv0 = tile * 64;
    const int buf = tile & 1;

    if (tile <= qt) {
      f32x4 sc[4] = {};
      __builtin_amdgcn_s_setprio(1);
#pragma unroll
      for (int kk = 0; kk < 4; ++kk) {
#pragma unroll
        for (int n = 0; n < 4; ++n) {
          int row = n*16 + l16;
          int g = kk*4 + lg;
          bf16x8 bk = *reinterpret_cast<const bf16x8*>(&Ks[buf][row*128 + ((g ^ (row & 7))<<3)]);
          sc[n] = __builtin_amdgcn_mfma_f32_16x16x32_bf16(bk, aq[kk], sc[n], 0, 0, 0);
        }
      }
      __builtin_amdgcn_s_setprio(0);
      if (tile == qt) {
        int qrow = q0 + l16;
#pragma unroll
        for (int n = 0; n < 4; ++n)
#pragma unroll
          for (int r = 0; r < 4; ++r) {
            int kidx = kv0 + n*16 + lg*4 + r;
            sc[n][r] = (kidx > qrow) ? -1e30f : sc[n][r];
          }
      }
      float mt = sc[0][0];
#pragma unroll
      for (int n = 0; n < 4; ++n)
#pragma unroll
        for (int r = 0; r < 4; ++r) mt = fmaxf(mt, sc[n][r]);
      mt = fmaxf(mt, __shfl_xor(mt, 16));
      mt = fmaxf(mt, __shfl_xor(mt, 32));
      if (__any(mt > mrun + 8.f)) {
        float mnew = fmaxf(mrun, mt);
        float alpha = __builtin_amdgcn_exp2f(mrun - mnew);
        mrun = mnew;
        lrun *= alpha;
        float ar[4];
#pragma unroll
        for (int r = 0; r < 4; ++r) ar[r] = __shfl(alpha, lg*4 + r);
#pragma unroll
        for (int n2 = 0; n2 < 8; ++n2)
#pragma unroll
          for (int r = 0; r < 4; ++r) o[n2][r] *= ar[r];
      }
      float rs = 0.f;
      unsigned pk[4][2];
#pragma unroll
      for (int n = 0; n < 4; ++n) {
        float p0 = __builtin_amdgcn_exp2f(sc[n][0] - mrun);
        float p1 = __builtin_amdgcn_exp2f(sc[n][1] - mrun);
        float p2 = __builtin_amdgcn_exp2f(sc[n][2] - mrun);
        float p3 = __builtin_amdgcn_exp2f(sc[n][3] - mrun);
        rs += (p0 + p1) + (p2 + p3);
        pk[n][0] = cvt_pk_bf16(p0, p1);
        pk[n][1] = cvt_pk_bf16(p2, p3);
      }
      rs += __shfl_xor(rs, 16);
      rs += __shfl_xor(rs, 32);
      lrun += rs;
      unsigned short* Pw = &Plds[w][0];
      char* Pb = (char*)Pw + l16*128;
#pragma unroll
      for (int n = 0; n < 4; ++n) {
        int sslot = (n*4 + lg) ^ (l16 & 14);
        *reinterpret_cast<uint2*>(Pb + sslot*8) = make_uint2(pk[n][0], pk[n][1]);
      }
      bf16x8 pa[2];
#pragma unroll
      for (int kk2 = 0; kk2 < 2; ++kk2) {
        int tp = (kk2*4 + lg) ^ ((l16 >> 1) & 7);
        pa[kk2] = *reinterpret_cast<const bf16x8*>(Pb + tp*16);
      }
      __builtin_amdgcn_s_setprio(1);
#pragma unroll
      for (int kk2 = 0; kk2 < 2; ++kk2) {
#pragma unroll
        for (int n2 = 0; n2 < 8; ++n2) {
          int d = n2*16 + l16;
          int g = kk2*4 + lg;
          bf16x8 bv = *reinterpret_cast<const bf16x8*>(&Vs[buf][d*64 + ((g ^ (d & 7))<<3)]);
          o[n2] = __builtin_amdgcn_mfma_f32_16x16x32_bf16(pa[kk2], bv, o[n2], 0, 0, 0);
        }
      }
      __builtin_amdgcn_s_setprio(0);
    }
  }
  float linv = 1.f / lrun;
  float lr[4];
#pragma unroll
  for (int r = 0; r < 4; ++r) lr[r] = __shfl(linv, lg*4 + r);
  size_t ob = ((size_t)b * S_) * D_;
#pragma unroll
  for (int n2 = 0; n2 < 8; ++n2) {
#pragma unroll
    for (int r = 0; r < 4; ++r) {
      int rowq = q0 + lg*4 + r;
      int d = n2*16 + l16;
      O[ob + (size_t)rowq * D_ + h*DH_ + d] = f2bf(o[n2][r] * lr[r]);
    }
  }
}

extern "C" void kernel_launch(void* const* d_in, const int* in_sizes, int n_in,
                              void* d_out, int out_size, void* d_ws, size_t ws_size,
                              hipStream_t stream) {
  const float* x    = (const float*)d_in[0];
  const float* fcos = (const float*)d_in[1];
  const float* fsin = (const float*)d_in[2];
  const float* wqkv = (const float*)d_in[4];
  const float* wo   = (const float*)d_in[5];
  float* out = (float*)d_out;
  char* ws = (char*)d_ws;

  unsigned short* xb    = (unsigned short*)(ws);                 // 16,777,216 B
  unsigned short* wqkvb = (unsigned short*)(ws + 16777216);      // 25,165,824 B
  unsigned short* wob   = (unsigned short*)(ws + 41943040);      //  8,388,608 B
  unsigned short* qkv   = (unsigned short*)(ws + 50331648);      // 33,554,432 B (compact QK, stride 4096)
  unsigned short* Kb    = (unsigned short*)(ws + 83886080);      // 16,777,216 B
  unsigned short* Vtb   = (unsigned short*)(ws + 100663296);     // 16,777,216 B (end 117,440,512)
  unsigned short* attn_out = xb;  // xb dead after gemm_qkv256 -> reuse

  cast3<<<dim3(24576), 256, 0, stream>>>(x, wqkv, wo, xb, wqkvb, wob);

  gemm_qkv256<<<dim3(32, 16), 512, 0, stream>>>(xb, wqkvb, qkv, Vtb);
  rope_k<<<dim3(4096), 256, 0, stream>>>(qkv, fcos, fsin, Kb);
  attn<<<dim3(16, 32), 512, 0, stream>>>(qkv, Kb, Vtb, fcos, fsin, attn_out);
  gemm_bt<<<dim3(16, 32), 256, 0, stream>>>(attn_out, wob, out, 2048, 2048);
}